// Round 8
// baseline (2072.264 us; speedup 1.0000x reference)
//
#include <hip/hip_runtime.h>
#include <hip/hip_bf16.h>

#define DEVI __device__ __forceinline__

typedef __bf16 bf16x8 __attribute__((ext_vector_type(8)));
typedef float f32x4 __attribute__((ext_vector_type(4)));

namespace {

constexpr int H = 2048;
constexpr int INTER = 8192;
constexpr int M_MOD = 2;
constexpr int N_TOK = 8192;
constexpr int G = N_TOK / M_MOD;   // 4096 tokens per modality
constexpr int UP_OUT = 2 * INTER;  // 16384

DEVI unsigned short f2bf(float f) {
  unsigned u = __builtin_bit_cast(unsigned, f);
  u += 0x7fffu + ((u >> 16) & 1u);  // round-to-nearest-even
  return (unsigned short)(u >> 16);
}

DEVI void gload_lds16(const void* g, void* lds) {
  __builtin_amdgcn_global_load_lds(
      (const __attribute__((address_space(1))) unsigned int*)g,
      (__attribute__((address_space(3))) unsigned int*)lds, 16, 0, 0);
}

DEVI void memfence_barrier() {
  asm volatile("" ::: "memory");
  __builtin_amdgcn_s_barrier();
  asm volatile("" ::: "memory");
}

__global__ __launch_bounds__(256) void cvt_f32_bf16(
    const float* __restrict__ in, unsigned short* __restrict__ out, int n4) {
  int idx = blockIdx.x * blockDim.x + threadIdx.x;
  int stride = gridDim.x * blockDim.x;
  for (int i = idx; i < n4; i += stride) {
    float4 v = ((const float4*)in)[i];
    ushort4 o;
    o.x = f2bf(v.x); o.y = f2bf(v.y); o.z = f2bf(v.z); o.w = f2bf(v.w);
    ((ushort4*)out)[i] = o;
  }
}

__global__ __launch_bounds__(256) void rmsnorm_kernel(
    const float* __restrict__ x, const float* __restrict__ w_norm,
    unsigned short* __restrict__ tm) {
  const int row = blockIdx.x;
  const int mod = row >> 12;  // 4096 rows per modality
  const int t = threadIdx.x;
  const float4* xr = (const float4*)(x + (size_t)row * H);
  const float4* wr = (const float4*)(w_norm + (size_t)mod * H);

  float4 v0 = xr[t];
  float4 v1 = xr[t + 256];
  float ss = v0.x * v0.x + v0.y * v0.y + v0.z * v0.z + v0.w * v0.w +
             v1.x * v1.x + v1.y * v1.y + v1.z * v1.z + v1.w * v1.w;
  #pragma unroll
  for (int o = 32; o > 0; o >>= 1) ss += __shfl_down(ss, o);
  __shared__ float red[4];
  const int w = t >> 6, l = t & 63;
  if (l == 0) red[w] = ss;
  __syncthreads();
  float tot = red[0] + red[1] + red[2] + red[3];
  float rn = rsqrtf(tot * (1.0f / H) + 1e-6f);

  float4 w0 = wr[t];
  float4 w1 = wr[t + 256];
  ushort4 o0, o1;
  o0.x = f2bf(v0.x * rn * (1.f + w0.x));
  o0.y = f2bf(v0.y * rn * (1.f + w0.y));
  o0.z = f2bf(v0.z * rn * (1.f + w0.z));
  o0.w = f2bf(v0.w * rn * (1.f + w0.w));
  o1.x = f2bf(v1.x * rn * (1.f + w1.x));
  o1.y = f2bf(v1.y * rn * (1.f + w1.y));
  o1.z = f2bf(v1.z * rn * (1.f + w1.z));
  o1.w = f2bf(v1.w * rn * (1.f + w1.w));
  ushort4* tr = (ushort4*)(tm + (size_t)row * H);
  tr[t] = o0;
  tr[t + 256] = o1;
}

// ---------------------------------------------------------------------------
// 256x256-tile 8-phase NT GEMM.  R8 = FULL-PHASE READ LEAD.
//
// R7 post-mortem: exposed LDS-read drain (~2400 cyc/K-tile-pair) serializes
// with MFMA because heavy read batches had <1 phase of lead (the 12-read
// batch's cover was one barrier).  Fix: separate a03 (array a) from a47
// (array a2) so every batch can be issued a FULL phase before consumption
// without register WAR.  Also fixes R7's latent race (reads after own vmcnt
// but before the publishing barrier).
//
// Per-pair schedule (tile T=2i in buf0, T+1 in buf1; stage slots = R6 set):
//  P0: rd b23(T);        stage h+7 ; BAR; MFMA Q0=a*b01  (0,0); BAR
//  P1: rd a47(T)->a2;    stage h+5 ; BAR; MFMA Q1=a*b23  (0,2); BAR
//  P2:                   stage h+10; BAR; MFMA Q2=a2*b01 (4,0); vmcnt(2); BAR
//  P3: rd a03,b01(T+1);  stage h+8 ; BAR; MFMA Q3=a2*b23 (4,2); BAR
//  P4: rd b23(T+1);      stage h+11; BAR; MFMA Q0'; BAR
//  P5: rd a47(T+1)->a2;  stage h+9 ; BAR; MFMA Q1'; BAR
//  P6:                   stage h+14; BAR; MFMA Q2'; vmcnt(2); BAR
//  P7: rd a03,b01(T+2);  stage h+12; BAR; MFMA Q3'; BAR
// Every read batch: issued >=1 phase (~800 cyc incl. MFMA cluster) before
// its consuming quad -> drains under the matrix pipe.
// vmcnt ledger (2 ops/stage, in-order): at P2-end outstanding =
// [h6,h4,h7,h5,h10]; vmcnt(2) retires {h6,h4,h7,h5} = tile T+1 exactly.
// At P6-end outstanding = [h10,h8,h11,h9,h14]; vmcnt(2) retires tile T+2.
// P3/P7 reads come AFTER the barrier following all-waves vmcnt -> formally
// published (fixes R7 race).  Register WAR: a written@P3/P7, last read
// Q1@P1/P5; a2 written@P1/P5, last read Q3@P3 prev; b01 written@P3/P7, last
// read Q2@P2/P6; b23 written@P0/P4, last read Q3@P3 prev — all safe.
// LDS WAR (stage vs read-service): every stage >=1 barrier after its
// region's reads are lgkm-serviced (service = before consuming quad's MFMA).
// Prologue: stages {0,1,2,3,6,4}; vmcnt(4) -> tile0 ready, keep [6,4];
// pre-read a03(0),b01(0) after barrier.  TAIL: stages wrap (h-=HMAX),
// HMAX%8==0 -> identical regions+ledger; last P7 reads garbage, never used.
// XOR swizzle: verified 0-conflict R2/R4-R7.
// EPI==0: fused swiglu7 -> bf16 (INTER ld). EPI==1: fp32 out (H ld).
// ---------------------------------------------------------------------------
template <int K, int CT_PER_MOD, int EPI>
__global__ __launch_bounds__(512, 2) void gemm8p(
    const unsigned short* __restrict__ A0, const unsigned short* __restrict__ B0,
    void* __restrict__ O0, long sAm, long sBm, long sOm) {
  __shared__ __align__(16) char smem[2][2][32768];

  constexpr int NT = K / 64;     // K-tiles (even for both instantiations)
  constexpr int HMAX = 4 * NT;   // half-tiles total (HMAX % 8 == 0)
  constexpr int NITER = NT / 2;
  constexpr int PER_MOD = 16 * CT_PER_MOD;  // 4096/256 = 16 row tiles
  constexpr int NWG = 2 * PER_MOD;
  constexpr int CPX = NWG / 8;

  // T1: bijective XCD swizzle (NWG % 8 == 0 for both instantiations)
  const int bid0 = blockIdx.x;
  const int bid = (bid0 % 8) * CPX + bid0 / 8;
  const int mod = bid / PER_MOD;
  const int q = bid % PER_MOD;
  const int ct = q / 16;  // col tile; rt inner so consecutive share B-panel
  const int rt = q % 16;

  const unsigned short* A = A0 + (long)mod * sAm;
  const unsigned short* B = B0 + (long)mod * sBm;

  const int t = threadIdx.x;
  const int w = t >> 6;
  const int l = t & 63;
  const int wr = w >> 2;  // 0..1
  const int wc = w & 3;   // 0..3

  const int fr = l & 15;
  const int fk = l >> 4;
  const int frx = (fr & 7) << 4;

  // ---- staging (per thread: 2 x gload_lds per half-tile)
  const unsigned short* gArow = A + (size_t)rt * 256 * K;
  const unsigned short* gBrow = B + (size_t)ct * 256 * K;
  const int srow = t >> 3;                        // 0..63
  const int scol = ((t & 7) ^ (srow & 7)) * 8;    // swizzled chunk (elements)

  // h = 4*tt + qq;  qq: 0=A-half0, 1=A-half1, 2=B-half0, 3=B-half1
  auto stage = [&](int h) {
    if (h >= HMAX) h -= HMAX;  // tail wrap: same regions, exact vmcnt ledger
    const int tt = h >> 2, qq = h & 3;
    const int isB = qq >> 1, half = qq & 1, buf = tt & 1;
    const unsigned short* src = (isB ? gBrow : gArow) +
        (size_t)(half * 128 + srow) * K + tt * 64 + scol;
    char* dst = smem[buf][isB] + half * 16384 + t * 16;
    gload_lds16(src, dst);
    gload_lds16(src + (size_t)64 * K, dst + 8192);
  };

  // ---- LDS fragment reads (swizzled)
  auto rdA = [&](const char* base, int mi, int ks) -> bf16x8 {
    const int row = wr * 128 + mi * 16 + fr;
    return *(const bf16x8*)(base + row * 128 + ((((ks << 2) + fk) << 4) ^ frx));
  };
  auto rdB = [&](const char* base, int ni, int ks) -> bf16x8 {
    const int row = wc * 64 + ni * 16 + fr;
    return *(const bf16x8*)(base + row * 128 + ((((ks << 2) + fk) << 4) ^ frx));
  };

  f32x4 acc[8][4];
  #pragma unroll
  for (int m = 0; m < 8; ++m)
    #pragma unroll
    for (int n = 0; n < 4; ++n) acc[m][n] = (f32x4){0.f, 0.f, 0.f, 0.f};

  bf16x8 a[4][2], a2[4][2], b[4][2];

#define MFMAQ(AR, MLO, NLO)                                                   \
  __builtin_amdgcn_s_setprio(1);                                              \
  _Pragma("unroll") for (int ks = 0; ks < 2; ++ks)                            \
  _Pragma("unroll") for (int mi = 0; mi < 4; ++mi)                            \
  _Pragma("unroll") for (int ni = 0; ni < 2; ++ni)                            \
    acc[(MLO) + mi][(NLO) + ni] = __builtin_amdgcn_mfma_f32_16x16x32_bf16(    \
        AR[mi][ks], b[(NLO) + ni][ks], acc[(MLO) + mi][(NLO) + ni], 0, 0, 0); \
  __builtin_amdgcn_s_setprio(0);

  // ---- prologue: tile0 + {h6, h4}; vmcnt(4) -> tile0 ready, keep [6,4]
  stage(0); stage(1); stage(2); stage(3);
  stage(6); stage(4);
  asm volatile("s_waitcnt vmcnt(4)" ::: "memory");
  memfence_barrier();

  const char* A0b = smem[0][0];
  const char* B0b = smem[0][1];
  const char* A1b = smem[1][0];
  const char* B1b = smem[1][1];

  // pre-read a03(0), b01(0) for iter0/P0
  #pragma unroll
  for (int mi = 0; mi < 4; ++mi)
    #pragma unroll
    for (int ks = 0; ks < 2; ++ks) a[mi][ks] = rdA(A0b, mi, ks);
  #pragma unroll
  for (int ni = 0; ni < 2; ++ni)
    #pragma unroll
    for (int ks = 0; ks < 2; ++ks) b[ni][ks] = rdB(B0b, ni, ks);

  for (int i = 0; i < NITER; ++i) {
    const int h0 = 8 * i;
    // ===== K-tile 2i (buf0) =====
    // P0: rd b23(2i) [lead->Q1@P1]; stage h+7; MFMA Q0 (a*b01)
    #pragma unroll
    for (int ni = 2; ni < 4; ++ni)
      #pragma unroll
      for (int ks = 0; ks < 2; ++ks) b[ni][ks] = rdB(B0b, ni, ks);
    stage(h0 + 7);
    memfence_barrier();
    MFMAQ(a, 0, 0);
    memfence_barrier();
    // P1: rd a47(2i)->a2 [lead->Q2@P2]; stage h+5; MFMA Q1 (a*b23)
    #pragma unroll
    for (int mi = 0; mi < 4; ++mi)
      #pragma unroll
      for (int ks = 0; ks < 2; ++ks) a2[mi][ks] = rdA(A0b, mi + 4, ks);
    stage(h0 + 5);
    memfence_barrier();
    MFMAQ(a, 0, 2);
    memfence_barrier();
    // P2: stage h+10; MFMA Q2 (a2*b01); vmcnt(2) retires tile 2i+1
    stage(h0 + 10);
    memfence_barrier();
    MFMAQ(a2, 4, 0);
    asm volatile("s_waitcnt vmcnt(2)" ::: "memory");
    memfence_barrier();
    // P3: rd a03,b01(2i+1) from buf1 (published by P2 vmcnt+barrier)
    //     [lead->Q0'@P4]; stage h+8; MFMA Q3 (a2*b23)
    stage(h0 + 8);
    #pragma unroll
    for (int mi = 0; mi < 4; ++mi)
      #pragma unroll
      for (int ks = 0; ks < 2; ++ks) a[mi][ks] = rdA(A1b, mi, ks);
    #pragma unroll
    for (int ni = 0; ni < 2; ++ni)
      #pragma unroll
      for (int ks = 0; ks < 2; ++ks) b[ni][ks] = rdB(B1b, ni, ks);
    memfence_barrier();
    MFMAQ(a2, 4, 2);
    memfence_barrier();

    // ===== K-tile 2i+1 (buf1) =====
    // P4: rd b23(2i+1); stage h+11; MFMA Q0'
    #pragma unroll
    for (int ni = 2; ni < 4; ++ni)
      #pragma unroll
      for (int ks = 0; ks < 2; ++ks) b[ni][ks] = rdB(B1b, ni, ks);
    stage(h0 + 11);
    memfence_barrier();
    MFMAQ(a, 0, 0);
    memfence_barrier();
    // P5: rd a47(2i+1)->a2; stage h+9; MFMA Q1'
    #pragma unroll
    for (int mi = 0; mi < 4; ++mi)
      #pragma unroll
      for (int ks = 0; ks < 2; ++ks) a2[mi][ks] = rdA(A1b, mi + 4, ks);
    stage(h0 + 9);
    memfence_barrier();
    MFMAQ(a, 0, 2);
    memfence_barrier();
    // P6: stage h+14; MFMA Q2'; vmcnt(2) retires tile 2i+2
    stage(h0 + 14);
    memfence_barrier();
    MFMAQ(a2, 4, 0);
    asm volatile("s_waitcnt vmcnt(2)" ::: "memory");
    memfence_barrier();
    // P7: rd a03,b01(2i+2) from buf0 (published); stage h+12; MFMA Q3'
    //     (last iter: reads wrapped garbage, never consumed)
    stage(h0 + 12);
    #pragma unroll
    for (int mi = 0; mi < 4; ++mi)
      #pragma unroll
      for (int ks = 0; ks < 2; ++ks) a[mi][ks] = rdA(A0b, mi, ks);
    #pragma unroll
    for (int ni = 0; ni < 2; ++ni)
      #pragma unroll
      for (int ks = 0; ks < 2; ++ks) b[ni][ks] = rdB(B0b, ni, ks);
    memfence_barrier();
    MFMAQ(a2, 4, 2);
    memfence_barrier();
  }
#undef MFMAQ

  // ---- epilogue.  C/D frag: col = l&15, row = (l>>4)*4 + j
  const int row0 = rt * 256 + wr * 128 + (l >> 4) * 4;
  const int col0 = ct * 256 + wc * 64 + (l & 15);
  if (EPI == 0) {
    unsigned short* Oa = (unsigned short*)O0 + (long)mod * sOm;
    #pragma unroll
    for (int m = 0; m < 8; ++m)
      #pragma unroll
      for (int n = 0; n < 4; ++n)
        #pragma unroll
        for (int j = 0; j < 4; ++j) {
          float y = acc[m][n][j];
          float p = __shfl_xor(y, 1);  // partner column (convergent)
          if (!(l & 1)) {
            float glu = fminf(y, 7.f);
            float lin = fminf(fmaxf(p, -7.f), 7.f);
            float sg = 1.f / (1.f + __expf(-1.702f * glu));
            float av = glu * sg * (lin + 1.f);
            Oa[(size_t)(row0 + m * 16 + j) * INTER + ((col0 + n * 16) >> 1)] = f2bf(av);
          }
        }
  } else {
    float* Oz = (float*)O0 + (long)mod * sOm;
    #pragma unroll
    for (int m = 0; m < 8; ++m)
      #pragma unroll
      for (int n = 0; n < 4; ++n)
        #pragma unroll
        for (int j = 0; j < 4; ++j)
          Oz[(size_t)(row0 + m * 16 + j) * H + (col0 + n * 16)] = acc[m][n][j];
  }
}

}  // namespace

extern "C" void kernel_launch(void* const* d_in, const int* in_sizes, int n_in,
                              void* d_out, int out_size, void* d_ws, size_t ws_size,
                              hipStream_t stream) {
  const float* x = (const float*)d_in[0];
  // d_in[1]: modality_mapping (int64) — tokens are pre-grouped in equal halves
  const float* w_norm = (const float*)d_in[2];
  const float* w_up = (const float*)d_in[3];
  const float* w_down = (const float*)d_in[4];

  char* ws = (char*)d_ws;
  unsigned short* wup_bf = (unsigned short*)ws;                  // 134217728 B
  unsigned short* wdn_bf = (unsigned short*)(ws + 134217728L);   //  67108864 B
  unsigned short* tm = (unsigned short*)(ws + 201326592L);       //  33554432 B
  unsigned short* abuf = (unsigned short*)(ws + 234881024L);     // 134217728 B
  // total ws use: 369098752 B

  cvt_f32_bf16<<<2048, 256, 0, stream>>>(w_up, wup_bf, (UP_OUT * M_MOD * H) / 4);
  cvt_f32_bf16<<<2048, 256, 0, stream>>>(w_down, wdn_bf, (H * M_MOD * INTER) / 4);
  rmsnorm_kernel<<<N_TOK, 256, 0, stream>>>(x, w_norm, tm);

  // up: M=4096, N=16384 (64 col tiles/mod), K=2048 -> 2048 blocks
  gemm8p<H, UP_OUT / 256, 0>
      <<<M_MOD * 16 * (UP_OUT / 256), 512, 0, stream>>>(
          tm, wup_bf, abuf, (long)G * H, (long)UP_OUT * H, (long)G * INTER);

  // down: M=4096, N=2048 (8 col tiles/mod), K=8192 -> 256 blocks
  gemm8p<INTER, H / 256, 1>
      <<<M_MOD * 16 * (H / 256), 512, 0, stream>>>(
          abuf, wdn_bf, d_out, (long)G * INTER, (long)H * INTER, (long)G * H);
}

// Round 9
// 852.842 us; speedup vs baseline: 2.4298x; 2.4298x over previous
//
#include <hip/hip_runtime.h>
#include <hip/hip_bf16.h>

#define DEVI __device__ __forceinline__

typedef __bf16 bf16x8 __attribute__((ext_vector_type(8)));
typedef float f32x4 __attribute__((ext_vector_type(4)));

namespace {

constexpr int H = 2048;
constexpr int INTER = 8192;
constexpr int M_MOD = 2;
constexpr int N_TOK = 8192;
constexpr int G = N_TOK / M_MOD;   // 4096 tokens per modality
constexpr int UP_OUT = 2 * INTER;  // 16384

DEVI unsigned short f2bf(float f) {
  unsigned u = __builtin_bit_cast(unsigned, f);
  u += 0x7fffu + ((u >> 16) & 1u);  // round-to-nearest-even
  return (unsigned short)(u >> 16);
}

DEVI void gload_lds16(const void* g, void* lds) {
  __builtin_amdgcn_global_load_lds(
      (const __attribute__((address_space(1))) unsigned int*)g,
      (__attribute__((address_space(3))) unsigned int*)lds, 16, 0, 0);
}

DEVI void memfence_barrier() {
  asm volatile("" ::: "memory");
  __builtin_amdgcn_s_barrier();
  asm volatile("" ::: "memory");
}

__global__ __launch_bounds__(256) void cvt_f32_bf16(
    const float* __restrict__ in, unsigned short* __restrict__ out, int n4) {
  int idx = blockIdx.x * blockDim.x + threadIdx.x;
  int stride = gridDim.x * blockDim.x;
  for (int i = idx; i < n4; i += stride) {
    float4 v = ((const float4*)in)[i];
    ushort4 o;
    o.x = f2bf(v.x); o.y = f2bf(v.y); o.z = f2bf(v.z); o.w = f2bf(v.w);
    ((ushort4*)out)[i] = o;
  }
}

__global__ __launch_bounds__(256) void rmsnorm_kernel(
    const float* __restrict__ x, const float* __restrict__ w_norm,
    unsigned short* __restrict__ tm) {
  const int row = blockIdx.x;
  const int mod = row >> 12;  // 4096 rows per modality
  const int t = threadIdx.x;
  const float4* xr = (const float4*)(x + (size_t)row * H);
  const float4* wr = (const float4*)(w_norm + (size_t)mod * H);

  float4 v0 = xr[t];
  float4 v1 = xr[t + 256];
  float ss = v0.x * v0.x + v0.y * v0.y + v0.z * v0.z + v0.w * v0.w +
             v1.x * v1.x + v1.y * v1.y + v1.z * v1.z + v1.w * v1.w;
  #pragma unroll
  for (int o = 32; o > 0; o >>= 1) ss += __shfl_down(ss, o);
  __shared__ float red[4];
  const int w = t >> 6, l = t & 63;
  if (l == 0) red[w] = ss;
  __syncthreads();
  float tot = red[0] + red[1] + red[2] + red[3];
  float rn = rsqrtf(tot * (1.0f / H) + 1e-6f);

  float4 w0 = wr[t];
  float4 w1 = wr[t + 256];
  ushort4 o0, o1;
  o0.x = f2bf(v0.x * rn * (1.f + w0.x));
  o0.y = f2bf(v0.y * rn * (1.f + w0.y));
  o0.z = f2bf(v0.z * rn * (1.f + w0.z));
  o0.w = f2bf(v0.w * rn * (1.f + w0.w));
  o1.x = f2bf(v1.x * rn * (1.f + w1.x));
  o1.y = f2bf(v1.y * rn * (1.f + w1.y));
  o1.z = f2bf(v1.z * rn * (1.f + w1.z));
  o1.w = f2bf(v1.w * rn * (1.f + w1.w));
  ushort4* tr = (ushort4*)(tm + (size_t)row * H);
  tr[t] = o0;
  tr[t + 256] = o1;
}

// ---------------------------------------------------------------------------
// 256x256-tile NT GEMM.  R9 = ks-SPLIT QUADS + LEAD-1 READS + 1 BARRIER/PHASE.
//
// R8 post-mortem: 96 frag regs spilled (hard 256-reg/wave cap for 512-thr
// blocks).  R9 stays at 64 frag regs (R6 footprint, proven no-spill):
// quads Q0=(mi0-3,ks0) Q1=(mi4-7,ks0) Q2=(mi0-3,ks1) Q3=(mi4-7,ks1), each
// 16 MFMA into distinct acc regs; rotation aF/aF2/bF/bF2 gives every
// within-tile read batch LEAD-1 (drains under previous quad's MFMA):
//  P0: rd a03ks0->aF, bks0->bF (8, same-phase: structural); stage h+4,h+7;
//      rd a47ks0->aF2 (lead Q1); Q0=aF*bF; BAR
//  P1: stage h+5; rd a03ks1->aF (lead Q2; old aF consumed by issued Q0);
//      rd bks1->bF2 (lead Q2,Q3); Q1=aF2*bF; BAR
//  P2: rd a47ks1->aF2 (lead Q3; old aF2 consumed by issued Q1);
//      Q2=aF*bF2; BAR
//  P3: stage h+10; Q3=aF2*bF2; vmcnt(2); BAR
//  P4-P7: mirror on buf1 (stages h+8,h+11 @P4; h+9 @P5; h+14 @P7).
// SINGLE barrier per phase (8/pair vs R6's 16): with lead-1, BARb(p-1)
// alone gives all WAR separation.  LDS-service audit (service of a read
// happens <= its consumer quad's phase-end barrier):
//  buf0-A: reads P0/P1/P2, last service <= BAR(P3) -> stages h+8@P4,h+9@P5 ok
//  buf0-B: bF@P0 (svc<=BAR(P0)), bF2@P1 (svc at Q2 <= BAR(P2)) -> h+10@P3,
//          h+11@P4 ok
//  buf1-A: last svc <= BAR(P7) -> h+4@P0',h+5@P1' ok
//  buf1-B: bF'@P4, bF2'@P5 (svc at Q2' <= BAR(P6)) -> h+14@P7, h+7@P0' ok
// gload_lds writes land after issue (>= the protecting barrier) -> safe.
// vmcnt ledger (2 ops/stage, in-order): entering P0 outstanding = {h+6};
// P0:+h+4,h+7; P1:+h+5; P3:+h+10 -> 10 ops; vmcnt(2)@P3 retires
// {h+6,h+4,h+7,h+5} = tile 2i+1 exactly (P4 then reads buf1).  Entering P4
// {h+10}; P4:+h+8,h+11; P5:+h+9; P7:+h+14 -> 10 ops; vmcnt(2)@P7 retires
// {h+10,h+8,h+11,h+9} = tile 2i+2 (next P0 reads buf0).  Stage flight >=2
// phases.  NO garbage reads (all reads are current-pair tiles); TAIL: only
// stages wrap (h-=HMAX), regions+ledger identical, wrapped data never read.
// Prologue: stage {0,1,2,3,6}; vmcnt(2) keeps h6; BAR.
// XOR swizzle: verified 0-conflict R2/R4-R8.
// EPI==0: fused swiglu7 -> bf16 (INTER ld). EPI==1: fp32 out (H ld).
// ---------------------------------------------------------------------------
template <int K, int CT_PER_MOD, int EPI>
__global__ __launch_bounds__(512, 2) void gemm8p(
    const unsigned short* __restrict__ A0, const unsigned short* __restrict__ B0,
    void* __restrict__ O0, long sAm, long sBm, long sOm) {
  __shared__ __align__(16) char smem[2][2][32768];

  constexpr int NT = K / 64;     // K-tiles (even for both instantiations)
  constexpr int HMAX = 4 * NT;   // half-tiles total (HMAX % 8 == 0)
  constexpr int NITER = NT / 2;
  constexpr int PER_MOD = 16 * CT_PER_MOD;  // 4096/256 = 16 row tiles
  constexpr int NWG = 2 * PER_MOD;
  constexpr int CPX = NWG / 8;

  // T1: bijective XCD swizzle (NWG % 8 == 0 for both instantiations)
  const int bid0 = blockIdx.x;
  const int bid = (bid0 % 8) * CPX + bid0 / 8;
  const int mod = bid / PER_MOD;
  const int q = bid % PER_MOD;
  const int ct = q / 16;  // col tile; rt inner so consecutive share B-panel
  const int rt = q % 16;

  const unsigned short* A = A0 + (long)mod * sAm;
  const unsigned short* B = B0 + (long)mod * sBm;

  const int t = threadIdx.x;
  const int w = t >> 6;
  const int l = t & 63;
  const int wr = w >> 2;  // 0..1
  const int wc = w & 3;   // 0..3

  const int fr = l & 15;
  const int fk = l >> 4;
  const int frx = (fr & 7) << 4;

  // ---- staging (per thread: 2 x gload_lds per half-tile)
  const unsigned short* gArow = A + (size_t)rt * 256 * K;
  const unsigned short* gBrow = B + (size_t)ct * 256 * K;
  const int srow = t >> 3;                        // 0..63
  const int scol = ((t & 7) ^ (srow & 7)) * 8;    // swizzled chunk (elements)

  // h = 4*tt + qq;  qq: 0=A-half0, 1=A-half1, 2=B-half0, 3=B-half1
  auto stage = [&](int h) {
    if (h >= HMAX) h -= HMAX;  // tail wrap: same regions, exact vmcnt ledger
    const int tt = h >> 2, qq = h & 3;
    const int isB = qq >> 1, half = qq & 1, buf = tt & 1;
    const unsigned short* src = (isB ? gBrow : gArow) +
        (size_t)(half * 128 + srow) * K + tt * 64 + scol;
    char* dst = smem[buf][isB] + half * 16384 + t * 16;
    gload_lds16(src, dst);
    gload_lds16(src + (size_t)64 * K, dst + 8192);
  };

  // ---- LDS fragment reads (swizzled)
  auto rdA = [&](const char* base, int mi, int ks) -> bf16x8 {
    const int row = wr * 128 + mi * 16 + fr;
    return *(const bf16x8*)(base + row * 128 + ((((ks << 2) + fk) << 4) ^ frx));
  };
  auto rdB = [&](const char* base, int ni, int ks) -> bf16x8 {
    const int row = wc * 64 + ni * 16 + fr;
    return *(const bf16x8*)(base + row * 128 + ((((ks << 2) + fk) << 4) ^ frx));
  };

  f32x4 acc[8][4];
  #pragma unroll
  for (int m = 0; m < 8; ++m)
    #pragma unroll
    for (int n = 0; n < 4; ++n) acc[m][n] = (f32x4){0.f, 0.f, 0.f, 0.f};

  bf16x8 aF[4], aF2[4], bF[4], bF2[4];

#define RDA4(DST, BASE, MLO, KS)                                              \
  _Pragma("unroll") for (int mi = 0; mi < 4; ++mi)                            \
      DST[mi] = rdA(BASE, (MLO) + mi, KS);
#define RDB4(DST, BASE, KS)                                                   \
  _Pragma("unroll") for (int ni = 0; ni < 4; ++ni) DST[ni] = rdB(BASE, ni, KS);
// 16 MFMA: one ks-slice of one mi-half across all 4 ni (distinct acc regs)
#define MFMAQ(AR, BR, MLO)                                                    \
  __builtin_amdgcn_s_setprio(1);                                              \
  _Pragma("unroll") for (int mi = 0; mi < 4; ++mi)                            \
  _Pragma("unroll") for (int ni = 0; ni < 4; ++ni)                            \
    acc[(MLO) + mi][ni] = __builtin_amdgcn_mfma_f32_16x16x32_bf16(            \
        AR[mi], BR[ni], acc[(MLO) + mi][ni], 0, 0, 0);                        \
  __builtin_amdgcn_s_setprio(0);

  // ---- prologue: tile0 (h0..h3) + h6; vmcnt(2) -> tile0 ready, keep {h6}
  stage(0); stage(1); stage(2); stage(3);
  stage(6);
  asm volatile("s_waitcnt vmcnt(2)" ::: "memory");
  memfence_barrier();

  const char* A0b = smem[0][0];
  const char* B0b = smem[0][1];
  const char* A1b = smem[1][0];
  const char* B1b = smem[1][1];

  for (int i = 0; i < NITER; ++i) {
    const int h0 = 8 * i;
    // ===== K-tile 2i (buf0) =====
    // P0
    RDA4(aF, A0b, 0, 0);
    RDB4(bF, B0b, 0);
    stage(h0 + 4); stage(h0 + 7);
    RDA4(aF2, A0b, 4, 0);           // lead -> Q1
    MFMAQ(aF, bF, 0);               // Q0
    memfence_barrier();
    // P1
    stage(h0 + 5);
    RDA4(aF, A0b, 0, 1);            // lead -> Q2 (old aF consumed: Q0 issued)
    RDB4(bF2, B0b, 1);              // lead -> Q2,Q3
    MFMAQ(aF2, bF, 4);              // Q1
    memfence_barrier();
    // P2
    RDA4(aF2, A0b, 4, 1);           // lead -> Q3 (old aF2 consumed: Q1 issued)
    MFMAQ(aF, bF2, 0);              // Q2
    memfence_barrier();
    // P3
    stage(h0 + 10);
    MFMAQ(aF2, bF2, 4);             // Q3
    asm volatile("s_waitcnt vmcnt(2)" ::: "memory");  // tile 2i+1 landed
    memfence_barrier();

    // ===== K-tile 2i+1 (buf1) =====
    // P4
    RDA4(aF, A1b, 0, 0);
    RDB4(bF, B1b, 0);
    stage(h0 + 8); stage(h0 + 11);
    RDA4(aF2, A1b, 4, 0);
    MFMAQ(aF, bF, 0);               // Q0'
    memfence_barrier();
    // P5
    stage(h0 + 9);
    RDA4(aF, A1b, 0, 1);
    RDB4(bF2, B1b, 1);
    MFMAQ(aF2, bF, 4);              // Q1'
    memfence_barrier();
    // P6
    RDA4(aF2, A1b, 4, 1);
    MFMAQ(aF, bF2, 0);              // Q2'
    memfence_barrier();
    // P7
    stage(h0 + 14);
    MFMAQ(aF2, bF2, 4);             // Q3'
    asm volatile("s_waitcnt vmcnt(2)" ::: "memory");  // tile 2i+2 landed
    memfence_barrier();
  }
#undef MFMAQ
#undef RDA4
#undef RDB4

  // ---- epilogue.  C/D frag: col = l&15, row = (l>>4)*4 + j
  const int row0 = rt * 256 + wr * 128 + (l >> 4) * 4;
  const int col0 = ct * 256 + wc * 64 + (l & 15);
  if (EPI == 0) {
    unsigned short* Oa = (unsigned short*)O0 + (long)mod * sOm;
    #pragma unroll
    for (int m = 0; m < 8; ++m)
      #pragma unroll
      for (int n = 0; n < 4; ++n)
        #pragma unroll
        for (int j = 0; j < 4; ++j) {
          float y = acc[m][n][j];
          float p = __shfl_xor(y, 1);  // partner column (convergent)
          if (!(l & 1)) {
            float glu = fminf(y, 7.f);
            float lin = fminf(fmaxf(p, -7.f), 7.f);
            float sg = 1.f / (1.f + __expf(-1.702f * glu));
            float av = glu * sg * (lin + 1.f);
            Oa[(size_t)(row0 + m * 16 + j) * INTER + ((col0 + n * 16) >> 1)] = f2bf(av);
          }
        }
  } else {
    float* Oz = (float*)O0 + (long)mod * sOm;
    #pragma unroll
    for (int m = 0; m < 8; ++m)
      #pragma unroll
      for (int n = 0; n < 4; ++n)
        #pragma unroll
        for (int j = 0; j < 4; ++j)
          Oz[(size_t)(row0 + m * 16 + j) * H + (col0 + n * 16)] = acc[m][n][j];
  }
}

}  // namespace

extern "C" void kernel_launch(void* const* d_in, const int* in_sizes, int n_in,
                              void* d_out, int out_size, void* d_ws, size_t ws_size,
                              hipStream_t stream) {
  const float* x = (const float*)d_in[0];
  // d_in[1]: modality_mapping (int64) — tokens are pre-grouped in equal halves
  const float* w_norm = (const float*)d_in[2];
  const float* w_up = (const float*)d_in[3];
  const float* w_down = (const float*)d_in[4];

  char* ws = (char*)d_ws;
  unsigned short* wup_bf = (unsigned short*)ws;                  // 134217728 B
  unsigned short* wdn_bf = (unsigned short*)(ws + 134217728L);   //  67108864 B
  unsigned short* tm = (unsigned short*)(ws + 201326592L);       //  33554432 B
  unsigned short* abuf = (unsigned short*)(ws + 234881024L);     // 134217728 B
  // total ws use: 369098752 B

  cvt_f32_bf16<<<2048, 256, 0, stream>>>(w_up, wup_bf, (UP_OUT * M_MOD * H) / 4);
  cvt_f32_bf16<<<2048, 256, 0, stream>>>(w_down, wdn_bf, (H * M_MOD * INTER) / 4);
  rmsnorm_kernel<<<N_TOK, 256, 0, stream>>>(x, w_norm, tm);

  // up: M=4096, N=16384 (64 col tiles/mod), K=2048 -> 2048 blocks
  gemm8p<H, UP_OUT / 256, 0>
      <<<M_MOD * 16 * (UP_OUT / 256), 512, 0, stream>>>(
          tm, wup_bf, abuf, (long)G * H, (long)UP_OUT * H, (long)G * INTER);

  // down: M=4096, N=2048 (8 col tiles/mod), K=8192 -> 256 blocks
  gemm8p<INTER, H / 256, 1>
      <<<M_MOD * 16 * (H / 256), 512, 0, stream>>>(
          abuf, wdn_bf, d_out, (long)G * INTER, (long)H * INTER, (long)G * H);
}